// Round 1
// baseline (405.839 us; speedup 1.0000x reference)
//
#include <hip/hip_runtime.h>
#include <hip/hip_bf16.h>
#include <stdint.h>

#define TT 16384
#define DD 768
#define EE 8
#define FF 469
#define FP 512

typedef __attribute__((ext_vector_type(8))) short s16x8;
typedef __attribute__((ext_vector_type(4))) float f32x4;

__device__ __forceinline__ ushort f2bf(float f) {
  uint32_t u = __builtin_bit_cast(uint32_t, f);
  u += 0x7fffu + ((u >> 16) & 1u);
  return (ushort)(u >> 16);
}

// ---------------- gating: fp32 logits, argmax, counts ----------------
__global__ void gate_kernel(const float* __restrict__ x, const float* __restrict__ Wg,
                            const float* __restrict__ bg, int* __restrict__ eidx,
                            int* __restrict__ counts) {
  int gt = blockIdx.x * blockDim.x + threadIdx.x;
  int wid = gt >> 6;
  int lane = gt & 63;
  if (wid >= TT) return;
  const float* xr = x + (size_t)wid * DD;
  float acc[EE];
#pragma unroll
  for (int e = 0; e < EE; ++e) acc[e] = 0.f;
  for (int d = lane; d < DD; d += 64) {
    float xv = xr[d];
#pragma unroll
    for (int e = 0; e < EE; ++e) acc[e] += xv * Wg[e * DD + d];
  }
#pragma unroll
  for (int off = 32; off > 0; off >>= 1) {
#pragma unroll
    for (int e = 0; e < EE; ++e) acc[e] += __shfl_down(acc[e], off);
  }
  if (lane == 0) {
    float best = acc[0] + bg[0];
    int bi = 0;
#pragma unroll
    for (int e = 1; e < EE; ++e) {
      float v = acc[e] + bg[e];
      if (v > best) { best = v; bi = e; }  // strict > keeps lowest index on ties (matches top_k)
    }
    eidx[wid] = bi;
    atomicAdd(&counts[bi], 1);
  }
}

__global__ void prefix_kernel(const int* __restrict__ counts, int* __restrict__ offs,
                              int* __restrict__ cursors) {
  if (threadIdx.x == 0 && blockIdx.x == 0) {
    int s = 0;
    for (int e = 0; e < EE; ++e) { offs[e] = s; cursors[e] = s; s += counts[e]; }
    offs[EE] = s;
  }
}

__global__ void scatter_kernel(const int* __restrict__ eidx, int* __restrict__ cursors,
                               int* __restrict__ perm) {
  int t = blockIdx.x * blockDim.x + threadIdx.x;
  if (t < TT) {
    int e = eidx[t];
    int p = atomicAdd(&cursors[e], 1);
    perm[p] = t;
  }
}

// ---------------- fp32 -> bf16 conversions ----------------
__global__ void convx_kernel(const float* __restrict__ x, ushort* __restrict__ xbf) {
  const int n4 = TT * DD / 4;
  for (int i = blockIdx.x * blockDim.x + threadIdx.x; i < n4; i += gridDim.x * blockDim.x) {
    float4 v = ((const float4*)x)[i];
    union { ushort u[4]; uint2 w; } p;
    p.u[0] = f2bf(v.x); p.u[1] = f2bf(v.y); p.u[2] = f2bf(v.z); p.u[3] = f2bf(v.w);
    ((uint2*)xbf)[i] = p.w;
  }
}

__global__ void convw12_kernel(const float* __restrict__ W1, const float* __restrict__ W2,
                               ushort* __restrict__ w1b, ushort* __restrict__ w2b) {
  const int n4 = EE * FP * (DD / 4);
  for (int i = blockIdx.x * blockDim.x + threadIdx.x; i < n4; i += gridDim.x * blockDim.x) {
    int d4 = i % (DD / 4);
    int ef = i / (DD / 4);
    int f = ef % FP;
    int e = ef / FP;
    union { ushort u[4]; uint2 w; } p1, p2;
    if (f < FF) {
      size_t src = ((size_t)e * FF + f) * DD;
      float4 v1 = ((const float4*)(W1 + src))[d4];
      float4 v2 = ((const float4*)(W2 + src))[d4];
      p1.u[0] = f2bf(v1.x); p1.u[1] = f2bf(v1.y); p1.u[2] = f2bf(v1.z); p1.u[3] = f2bf(v1.w);
      p2.u[0] = f2bf(v2.x); p2.u[1] = f2bf(v2.y); p2.u[2] = f2bf(v2.z); p2.u[3] = f2bf(v2.w);
    } else {
      p1.w.x = 0u; p1.w.y = 0u; p2.w.x = 0u; p2.w.y = 0u;
    }
    ((uint2*)w1b)[i] = p1.w;
    ((uint2*)w2b)[i] = p2.w;
  }
}

__global__ void convw3_kernel(const float* __restrict__ W3, ushort* __restrict__ w3b) {
  const int n = EE * DD * FP;
  for (int i = blockIdx.x * blockDim.x + threadIdx.x; i < n; i += gridDim.x * blockDim.x) {
    int f = i % FP;
    int ed = i / FP;  // e*DD + d
    float v = (f < FF) ? W3[(size_t)ed * FF + f] : 0.f;
    w3b[i] = f2bf(v);
  }
}

// ---------------- grouped GEMM1: u = Xg@W1^T, v = Xg@W2^T, h = silu(u)*v ----------------
__global__ __launch_bounds__(256) void ffn1_kernel(
    const ushort* __restrict__ xbf, const ushort* __restrict__ w1b,
    const ushort* __restrict__ w2b, const int* __restrict__ perm,
    const int* __restrict__ offs, ushort* __restrict__ hbf) {
  int e = blockIdx.z;
  int gOff = offs[e];
  int Ne = offs[e + 1] - gOff;
  int tile0 = blockIdx.x * 64;
  if (tile0 >= Ne) return;
  int f0 = blockIdx.y * 64;

  __shared__ __align__(16) short As[64 * 40];
  __shared__ __align__(16) short B1s[64 * 40];
  __shared__ __align__(16) short B2s[64 * 40];

  int tid = threadIdx.x;
  int row = tid >> 2;
  int seg = tid & 3;

  int gidx = gOff + tile0 + row;
  if (gidx >= TT) gidx = TT - 1;
  int tok = perm[gidx];
  const ushort* abase = xbf + (size_t)tok * DD + seg * 8;
  const ushort* b1base = w1b + ((size_t)e * FP + f0 + row) * DD + seg * 8;
  const ushort* b2base = w2b + ((size_t)e * FP + f0 + row) * DD + seg * 8;
  short* adst = &As[row * 40 + seg * 8];
  short* b1dst = &B1s[row * 40 + seg * 8];
  short* b2dst = &B2s[row * 40 + seg * 8];

  int lane = tid & 63;
  int w = tid >> 6;
  int wr = w >> 1, wc = w & 1;
  int lrow = lane & 15;
  int khalf = lane >> 4;
  int koff = khalf * 8;

  f32x4 accu[2][2], accv[2][2];
  f32x4 zero = {0.f, 0.f, 0.f, 0.f};
#pragma unroll
  for (int mi = 0; mi < 2; ++mi)
#pragma unroll
    for (int ni = 0; ni < 2; ++ni) { accu[mi][ni] = zero; accv[mi][ni] = zero; }

  const short* ard = &As[(wr * 32 + lrow) * 40 + koff];
  const short* b1rd = &B1s[(wc * 32 + lrow) * 40 + koff];
  const short* b2rd = &B2s[(wc * 32 + lrow) * 40 + koff];

  for (int k0 = 0; k0 < DD; k0 += 32) {
    *(int4*)adst = *(const int4*)(abase + k0);
    *(int4*)b1dst = *(const int4*)(b1base + k0);
    *(int4*)b2dst = *(const int4*)(b2base + k0);
    __syncthreads();
    s16x8 a0 = *(const s16x8*)(ard);
    s16x8 a1 = *(const s16x8*)(ard + 16 * 40);
    s16x8 b10 = *(const s16x8*)(b1rd);
    s16x8 b11 = *(const s16x8*)(b1rd + 16 * 40);
    s16x8 b20 = *(const s16x8*)(b2rd);
    s16x8 b21 = *(const s16x8*)(b2rd + 16 * 40);
    accu[0][0] = __builtin_amdgcn_mfma_f32_16x16x32_bf16(a0, b10, accu[0][0], 0, 0, 0);
    accu[0][1] = __builtin_amdgcn_mfma_f32_16x16x32_bf16(a0, b11, accu[0][1], 0, 0, 0);
    accu[1][0] = __builtin_amdgcn_mfma_f32_16x16x32_bf16(a1, b10, accu[1][0], 0, 0, 0);
    accu[1][1] = __builtin_amdgcn_mfma_f32_16x16x32_bf16(a1, b11, accu[1][1], 0, 0, 0);
    accv[0][0] = __builtin_amdgcn_mfma_f32_16x16x32_bf16(a0, b20, accv[0][0], 0, 0, 0);
    accv[0][1] = __builtin_amdgcn_mfma_f32_16x16x32_bf16(a0, b21, accv[0][1], 0, 0, 0);
    accv[1][0] = __builtin_amdgcn_mfma_f32_16x16x32_bf16(a1, b20, accv[1][0], 0, 0, 0);
    accv[1][1] = __builtin_amdgcn_mfma_f32_16x16x32_bf16(a1, b21, accv[1][1], 0, 0, 0);
    __syncthreads();
  }

#pragma unroll
  for (int mi = 0; mi < 2; ++mi) {
#pragma unroll
    for (int ni = 0; ni < 2; ++ni) {
#pragma unroll
      for (int r = 0; r < 4; ++r) {
        int rowin = wr * 32 + mi * 16 + khalf * 4 + r;
        int gr = tile0 + rowin;
        if (gr < Ne) {
          float uu = accu[mi][ni][r];
          float vv = accv[mi][ni][r];
          float hh = (uu / (1.f + __expf(-uu))) * vv;
          int col = f0 + wc * 32 + ni * 16 + lrow;
          hbf[(size_t)(gOff + gr) * FP + col] = f2bf(hh);
        }
      }
    }
  }
}

// ---------------- grouped GEMM2: OUT = H@W3^T, scattered to token rows ----------------
__global__ __launch_bounds__(256) void ffn2_kernel(
    const ushort* __restrict__ hbf, const ushort* __restrict__ w3b,
    const int* __restrict__ perm, const int* __restrict__ offs,
    float* __restrict__ out) {
  int e = blockIdx.z;
  int gOff = offs[e];
  int Ne = offs[e + 1] - gOff;
  int tile0 = blockIdx.x * 64;
  if (tile0 >= Ne) return;
  int d0 = blockIdx.y * 64;

  __shared__ __align__(16) short As[64 * 40];
  __shared__ __align__(16) short Bs[64 * 40];

  int tid = threadIdx.x;
  int row = tid >> 2;
  int seg = tid & 3;

  int p = gOff + tile0 + row;
  if (p >= TT) p = TT - 1;
  const ushort* abase = hbf + (size_t)p * FP + seg * 8;
  const ushort* bbase = w3b + ((size_t)e * DD + d0 + row) * FP + seg * 8;
  short* adst = &As[row * 40 + seg * 8];
  short* bdst = &Bs[row * 40 + seg * 8];

  int lane = tid & 63;
  int w = tid >> 6;
  int wr = w >> 1, wc = w & 1;
  int lrow = lane & 15;
  int khalf = lane >> 4;
  int koff = khalf * 8;

  f32x4 acc[2][2];
  f32x4 zero = {0.f, 0.f, 0.f, 0.f};
#pragma unroll
  for (int mi = 0; mi < 2; ++mi)
#pragma unroll
    for (int ni = 0; ni < 2; ++ni) acc[mi][ni] = zero;

  const short* ard = &As[(wr * 32 + lrow) * 40 + koff];
  const short* brd = &Bs[(wc * 32 + lrow) * 40 + koff];

  for (int k0 = 0; k0 < FP; k0 += 32) {
    *(int4*)adst = *(const int4*)(abase + k0);
    *(int4*)bdst = *(const int4*)(bbase + k0);
    __syncthreads();
    s16x8 a0 = *(const s16x8*)(ard);
    s16x8 a1 = *(const s16x8*)(ard + 16 * 40);
    s16x8 b0 = *(const s16x8*)(brd);
    s16x8 b1 = *(const s16x8*)(brd + 16 * 40);
    acc[0][0] = __builtin_amdgcn_mfma_f32_16x16x32_bf16(a0, b0, acc[0][0], 0, 0, 0);
    acc[0][1] = __builtin_amdgcn_mfma_f32_16x16x32_bf16(a0, b1, acc[0][1], 0, 0, 0);
    acc[1][0] = __builtin_amdgcn_mfma_f32_16x16x32_bf16(a1, b0, acc[1][0], 0, 0, 0);
    acc[1][1] = __builtin_amdgcn_mfma_f32_16x16x32_bf16(a1, b1, acc[1][1], 0, 0, 0);
    __syncthreads();
  }

#pragma unroll
  for (int mi = 0; mi < 2; ++mi) {
#pragma unroll
    for (int ni = 0; ni < 2; ++ni) {
#pragma unroll
      for (int r = 0; r < 4; ++r) {
        int rowin = wr * 32 + mi * 16 + khalf * 4 + r;
        int gr = tile0 + rowin;
        if (gr < Ne) {
          int t = perm[gOff + gr];
          int col = d0 + wc * 32 + ni * 16 + lrow;
          out[(size_t)t * DD + col] = acc[mi][ni][r];
        }
      }
    }
  }
}

extern "C" void kernel_launch(void* const* d_in, const int* in_sizes, int n_in,
                              void* d_out, int out_size, void* d_ws, size_t ws_size,
                              hipStream_t stream) {
  const float* x = (const float*)d_in[0];
  const float* Wg = (const float*)d_in[1];
  const float* bg = (const float*)d_in[2];
  const float* W1 = (const float*)d_in[3];
  const float* W2 = (const float*)d_in[4];
  const float* W3 = (const float*)d_in[5];
  float* out = (float*)d_out;

  char* ws = (char*)d_ws;
  int* eidx = (int*)ws;                       // TT ints
  int* perm = (int*)(ws + 65536);             // TT ints
  int* counts = (int*)(ws + 131072);          // 16 ints
  int* offs = (int*)(ws + 131072 + 64);       // 9 ints
  int* cursors = (int*)(ws + 131072 + 128);   // 8 ints
  ushort* xbf = (ushort*)(ws + 262144);
  ushort* w1b = xbf + (size_t)TT * DD;
  ushort* w2b = w1b + (size_t)EE * FP * DD;
  ushort* w3b = w2b + (size_t)EE * FP * DD;
  ushort* hbf = w3b + (size_t)EE * DD * FP;

  hipMemsetAsync(counts, 0, 64, stream);
  convx_kernel<<<2048, 256, 0, stream>>>(x, xbf);
  convw12_kernel<<<2048, 256, 0, stream>>>(W1, W2, w1b, w2b);
  convw3_kernel<<<2048, 256, 0, stream>>>(W3, w3b);
  gate_kernel<<<TT / 4, 256, 0, stream>>>(x, Wg, bg, eidx, counts);
  prefix_kernel<<<1, 64, 0, stream>>>(counts, offs, cursors);
  scatter_kernel<<<TT / 256, 256, 0, stream>>>(eidx, cursors, perm);
  ffn1_kernel<<<dim3(TT / 64, FP / 64, EE), 256, 0, stream>>>(xbf, w1b, w2b, perm, offs, hbf);
  ffn2_kernel<<<dim3(TT / 64, DD / 64, EE), 256, 0, stream>>>(hbf, w3b, perm, offs, out);
}

// Round 2
// 150.237 us; speedup vs baseline: 2.7013x; 2.7013x over previous
//
#include <hip/hip_runtime.h>
#include <hip/hip_bf16.h>
#include <stdint.h>

#define TT 16384
#define DD 768
#define EE 8
#define FF 469
#define FP 512
#define NCHUNK (TT / 64)   // 256 chunks of 64 tokens

typedef __attribute__((ext_vector_type(8))) short s16x8;
typedef __attribute__((ext_vector_type(4))) float f32x4;

__device__ __forceinline__ ushort f2bf(float f) {
  uint32_t u = __builtin_bit_cast(uint32_t, f);
  u += 0x7fffu + ((u >> 16) & 1u);
  return (ushort)(u >> 16);
}

// ---------------- fused gating (fp32) + x->bf16 conversion; NO atomics ----------------
__global__ __launch_bounds__(256) void gate_conv_kernel(
    const float* __restrict__ x, const float* __restrict__ Wg,
    const float* __restrict__ bg, int* __restrict__ eidx,
    ushort* __restrict__ xbf) {
  __shared__ float4 wgs[EE * DD / 4];  // 24 KB
  int tid = threadIdx.x;
  for (int i = tid; i < EE * DD / 4; i += 256) wgs[i] = ((const float4*)Wg)[i];
  __syncthreads();

  int t = blockIdx.x * 4 + (tid >> 6);
  int lane = tid & 63;
  const float4* xr = (const float4*)(x + (size_t)t * DD);
  float4 xv[3];
#pragma unroll
  for (int k = 0; k < 3; ++k) xv[k] = xr[lane + 64 * k];

  float acc[EE];
#pragma unroll
  for (int e = 0; e < EE; ++e) acc[e] = 0.f;
#pragma unroll
  for (int k = 0; k < 3; ++k) {
#pragma unroll
    for (int e = 0; e < EE; ++e) {
      float4 w = wgs[e * 192 + lane + 64 * k];
      acc[e] += xv[k].x * w.x + xv[k].y * w.y + xv[k].z * w.z + xv[k].w * w.w;
    }
  }

  // bf16 conversion of the x data we already hold in registers
  uint2* xd = (uint2*)(xbf + (size_t)t * DD);
#pragma unroll
  for (int k = 0; k < 3; ++k) {
    union { ushort u[4]; uint2 w; } p;
    p.u[0] = f2bf(xv[k].x); p.u[1] = f2bf(xv[k].y);
    p.u[2] = f2bf(xv[k].z); p.u[3] = f2bf(xv[k].w);
    xd[lane + 64 * k] = p.w;
  }

  // wave reduction of 8 logits
#pragma unroll
  for (int off = 32; off; off >>= 1) {
#pragma unroll
    for (int e = 0; e < EE; ++e) acc[e] += __shfl_down(acc[e], off);
  }
  if (lane == 0) {
    float best = acc[0] + bg[0];
    int bi = 0;
#pragma unroll
    for (int e = 1; e < EE; ++e) {
      float v = acc[e] + bg[e];
      if (v > best) { best = v; bi = e; }  // strict > : lowest index wins ties (matches top_k)
    }
    eidx[t] = bi;
  }
}

// ---------------- ballot histogram: per-chunk per-expert counts, no atomics ----------------
__global__ void hist_kernel(const int* __restrict__ eidx, int* __restrict__ cnt) {
  int c = blockIdx.x * 4 + (threadIdx.x >> 6);
  int lane = threadIdx.x & 63;
  int v = eidx[c * 64 + lane];
#pragma unroll
  for (int e = 0; e < EE; ++e) {
    unsigned long long me = __ballot(v == e);
    if (lane == 0) cnt[e * NCHUNK + c] = __popcll(me);
  }
}

// ---------------- wave-parallel exclusive scan: 8 waves, one per expert ----------------
__global__ void scan_kernel(const int* __restrict__ cnt, int* __restrict__ scanEx,
                            int* __restrict__ offs) {
  int e = threadIdx.x >> 6;
  int lane = threadIdx.x & 63;
  __shared__ int totals[EE];
  int carry = 0;
#pragma unroll
  for (int g = 0; g < NCHUNK / 64; ++g) {
    int v = cnt[e * NCHUNK + g * 64 + lane];
    int s = v;
#pragma unroll
    for (int d = 1; d < 64; d <<= 1) {
      int t = __shfl_up(s, d);
      if (lane >= d) s += t;
    }
    scanEx[e * NCHUNK + g * 64 + lane] = carry + s - v;
    carry += __shfl(s, 63);
  }
  if (lane == 0) totals[e] = carry;
  __syncthreads();
  if (threadIdx.x == 0) {
    int s = 0;
    for (int e2 = 0; e2 < EE; ++e2) { offs[e2] = s; s += totals[e2]; }
    offs[EE] = s;
  }
}

// ---------------- scatter via in-chunk ballot rank, no atomics ----------------
__global__ void scatter2_kernel(const int* __restrict__ eidx, const int* __restrict__ offs,
                                const int* __restrict__ scanEx, int* __restrict__ perm) {
  int c = blockIdx.x * 4 + (threadIdx.x >> 6);
  int lane = threadIdx.x & 63;
  int t = c * 64 + lane;
  int v = eidx[t];
  unsigned long long mym = 0;
#pragma unroll
  for (int e = 0; e < EE; ++e) {
    unsigned long long me = __ballot(v == e);
    if (v == e) mym = me;
  }
  int rank = __popcll(mym & ((1ULL << lane) - 1ULL));
  perm[offs[v] + scanEx[v * NCHUNK + c] + rank] = t;
}

// ---------------- weight fp32 -> bf16 conversions ----------------
__global__ void convw12_kernel(const float* __restrict__ W1, const float* __restrict__ W2,
                               ushort* __restrict__ w1b, ushort* __restrict__ w2b) {
  const int n4 = EE * FP * (DD / 4);
  for (int i = blockIdx.x * blockDim.x + threadIdx.x; i < n4; i += gridDim.x * blockDim.x) {
    int d4 = i % (DD / 4);
    int ef = i / (DD / 4);
    int f = ef % FP;
    int e = ef / FP;
    union { ushort u[4]; uint2 w; } p1, p2;
    if (f < FF) {
      size_t src = ((size_t)e * FF + f) * DD;
      float4 v1 = ((const float4*)(W1 + src))[d4];
      float4 v2 = ((const float4*)(W2 + src))[d4];
      p1.u[0] = f2bf(v1.x); p1.u[1] = f2bf(v1.y); p1.u[2] = f2bf(v1.z); p1.u[3] = f2bf(v1.w);
      p2.u[0] = f2bf(v2.x); p2.u[1] = f2bf(v2.y); p2.u[2] = f2bf(v2.z); p2.u[3] = f2bf(v2.w);
    } else {
      p1.w.x = 0u; p1.w.y = 0u; p2.w.x = 0u; p2.w.y = 0u;
    }
    ((uint2*)w1b)[i] = p1.w;
    ((uint2*)w2b)[i] = p2.w;
  }
}

__global__ void convw3_kernel(const float* __restrict__ W3, ushort* __restrict__ w3b) {
  const int n = EE * DD * FP;
  for (int i = blockIdx.x * blockDim.x + threadIdx.x; i < n; i += gridDim.x * blockDim.x) {
    int f = i % FP;
    int ed = i / FP;  // e*DD + d
    float v = (f < FF) ? W3[(size_t)ed * FF + f] : 0.f;
    w3b[i] = f2bf(v);
  }
}

// ---------------- grouped GEMM1: u = Xg@W1^T, v = Xg@W2^T, h = silu(u)*v ----------------
__global__ __launch_bounds__(256) void ffn1_kernel(
    const ushort* __restrict__ xbf, const ushort* __restrict__ w1b,
    const ushort* __restrict__ w2b, const int* __restrict__ perm,
    const int* __restrict__ offs, ushort* __restrict__ hbf) {
  int e = blockIdx.z;
  int gOff = offs[e];
  int Ne = offs[e + 1] - gOff;
  int tile0 = blockIdx.x * 64;
  if (tile0 >= Ne) return;
  int f0 = blockIdx.y * 64;

  __shared__ __align__(16) short As[64 * 40];
  __shared__ __align__(16) short B1s[64 * 40];
  __shared__ __align__(16) short B2s[64 * 40];

  int tid = threadIdx.x;
  int row = tid >> 2;
  int seg = tid & 3;

  int gidx = gOff + tile0 + row;
  if (gidx >= TT) gidx = TT - 1;
  int tok = perm[gidx];
  const ushort* abase = xbf + (size_t)tok * DD + seg * 8;
  const ushort* b1base = w1b + ((size_t)e * FP + f0 + row) * DD + seg * 8;
  const ushort* b2base = w2b + ((size_t)e * FP + f0 + row) * DD + seg * 8;
  short* adst = &As[row * 40 + seg * 8];
  short* b1dst = &B1s[row * 40 + seg * 8];
  short* b2dst = &B2s[row * 40 + seg * 8];

  int lane = tid & 63;
  int w = tid >> 6;
  int wr = w >> 1, wc = w & 1;
  int lrow = lane & 15;
  int khalf = lane >> 4;
  int koff = khalf * 8;

  f32x4 accu[2][2], accv[2][2];
  f32x4 zero = {0.f, 0.f, 0.f, 0.f};
#pragma unroll
  for (int mi = 0; mi < 2; ++mi)
#pragma unroll
    for (int ni = 0; ni < 2; ++ni) { accu[mi][ni] = zero; accv[mi][ni] = zero; }

  const short* ard = &As[(wr * 32 + lrow) * 40 + koff];
  const short* b1rd = &B1s[(wc * 32 + lrow) * 40 + koff];
  const short* b2rd = &B2s[(wc * 32 + lrow) * 40 + koff];

  for (int k0 = 0; k0 < DD; k0 += 32) {
    *(int4*)adst = *(const int4*)(abase + k0);
    *(int4*)b1dst = *(const int4*)(b1base + k0);
    *(int4*)b2dst = *(const int4*)(b2base + k0);
    __syncthreads();
    s16x8 a0 = *(const s16x8*)(ard);
    s16x8 a1 = *(const s16x8*)(ard + 16 * 40);
    s16x8 b10 = *(const s16x8*)(b1rd);
    s16x8 b11 = *(const s16x8*)(b1rd + 16 * 40);
    s16x8 b20 = *(const s16x8*)(b2rd);
    s16x8 b21 = *(const s16x8*)(b2rd + 16 * 40);
    accu[0][0] = __builtin_amdgcn_mfma_f32_16x16x32_bf16(a0, b10, accu[0][0], 0, 0, 0);
    accu[0][1] = __builtin_amdgcn_mfma_f32_16x16x32_bf16(a0, b11, accu[0][1], 0, 0, 0);
    accu[1][0] = __builtin_amdgcn_mfma_f32_16x16x32_bf16(a1, b10, accu[1][0], 0, 0, 0);
    accu[1][1] = __builtin_amdgcn_mfma_f32_16x16x32_bf16(a1, b11, accu[1][1], 0, 0, 0);
    accv[0][0] = __builtin_amdgcn_mfma_f32_16x16x32_bf16(a0, b20, accv[0][0], 0, 0, 0);
    accv[0][1] = __builtin_amdgcn_mfma_f32_16x16x32_bf16(a0, b21, accv[0][1], 0, 0, 0);
    accv[1][0] = __builtin_amdgcn_mfma_f32_16x16x32_bf16(a1, b20, accv[1][0], 0, 0, 0);
    accv[1][1] = __builtin_amdgcn_mfma_f32_16x16x32_bf16(a1, b21, accv[1][1], 0, 0, 0);
    __syncthreads();
  }

#pragma unroll
  for (int mi = 0; mi < 2; ++mi) {
#pragma unroll
    for (int ni = 0; ni < 2; ++ni) {
#pragma unroll
      for (int r = 0; r < 4; ++r) {
        int rowin = wr * 32 + mi * 16 + khalf * 4 + r;
        int gr = tile0 + rowin;
        if (gr < Ne) {
          float uu = accu[mi][ni][r];
          float vv = accv[mi][ni][r];
          float hh = (uu / (1.f + __expf(-uu))) * vv;
          int col = f0 + wc * 32 + ni * 16 + lrow;
          hbf[(size_t)(gOff + gr) * FP + col] = f2bf(hh);
        }
      }
    }
  }
}

// ---------------- grouped GEMM2: OUT = H@W3^T, scattered to token rows ----------------
__global__ __launch_bounds__(256) void ffn2_kernel(
    const ushort* __restrict__ hbf, const ushort* __restrict__ w3b,
    const int* __restrict__ perm, const int* __restrict__ offs,
    float* __restrict__ out) {
  int e = blockIdx.z;
  int gOff = offs[e];
  int Ne = offs[e + 1] - gOff;
  int tile0 = blockIdx.x * 64;
  if (tile0 >= Ne) return;
  int d0 = blockIdx.y * 64;

  __shared__ __align__(16) short As[64 * 40];
  __shared__ __align__(16) short Bs[64 * 40];

  int tid = threadIdx.x;
  int row = tid >> 2;
  int seg = tid & 3;

  int p = gOff + tile0 + row;
  if (p >= TT) p = TT - 1;
  const ushort* abase = hbf + (size_t)p * FP + seg * 8;
  const ushort* bbase = w3b + ((size_t)e * DD + d0 + row) * FP + seg * 8;
  short* adst = &As[row * 40 + seg * 8];
  short* bdst = &Bs[row * 40 + seg * 8];

  int lane = tid & 63;
  int w = tid >> 6;
  int wr = w >> 1, wc = w & 1;
  int lrow = lane & 15;
  int khalf = lane >> 4;
  int koff = khalf * 8;

  f32x4 acc[2][2];
  f32x4 zero = {0.f, 0.f, 0.f, 0.f};
#pragma unroll
  for (int mi = 0; mi < 2; ++mi)
#pragma unroll
    for (int ni = 0; ni < 2; ++ni) acc[mi][ni] = zero;

  const short* ard = &As[(wr * 32 + lrow) * 40 + koff];
  const short* brd = &Bs[(wc * 32 + lrow) * 40 + koff];

  for (int k0 = 0; k0 < FP; k0 += 32) {
    *(int4*)adst = *(const int4*)(abase + k0);
    *(int4*)bdst = *(const int4*)(bbase + k0);
    __syncthreads();
    s16x8 a0 = *(const s16x8*)(ard);
    s16x8 a1 = *(const s16x8*)(ard + 16 * 40);
    s16x8 b0 = *(const s16x8*)(brd);
    s16x8 b1 = *(const s16x8*)(brd + 16 * 40);
    acc[0][0] = __builtin_amdgcn_mfma_f32_16x16x32_bf16(a0, b0, acc[0][0], 0, 0, 0);
    acc[0][1] = __builtin_amdgcn_mfma_f32_16x16x32_bf16(a0, b1, acc[0][1], 0, 0, 0);
    acc[1][0] = __builtin_amdgcn_mfma_f32_16x16x32_bf16(a1, b0, acc[1][0], 0, 0, 0);
    acc[1][1] = __builtin_amdgcn_mfma_f32_16x16x32_bf16(a1, b1, acc[1][1], 0, 0, 0);
    __syncthreads();
  }

#pragma unroll
  for (int mi = 0; mi < 2; ++mi) {
#pragma unroll
    for (int ni = 0; ni < 2; ++ni) {
#pragma unroll
      for (int r = 0; r < 4; ++r) {
        int rowin = wr * 32 + mi * 16 + khalf * 4 + r;
        int gr = tile0 + rowin;
        if (gr < Ne) {
          int t = perm[gOff + gr];
          int col = d0 + wc * 32 + ni * 16 + lrow;
          out[(size_t)t * DD + col] = acc[mi][ni][r];
        }
      }
    }
  }
}

extern "C" void kernel_launch(void* const* d_in, const int* in_sizes, int n_in,
                              void* d_out, int out_size, void* d_ws, size_t ws_size,
                              hipStream_t stream) {
  const float* x = (const float*)d_in[0];
  const float* Wg = (const float*)d_in[1];
  const float* bg = (const float*)d_in[2];
  const float* W1 = (const float*)d_in[3];
  const float* W2 = (const float*)d_in[4];
  const float* W3 = (const float*)d_in[5];
  float* out = (float*)d_out;

  char* ws = (char*)d_ws;
  int* eidx = (int*)ws;                          // TT ints (64 KB)
  int* perm = (int*)(ws + 65536);                // TT ints (64 KB)
  int* offs = (int*)(ws + 131072);               // 9 ints
  int* cnt = (int*)(ws + 131072 + 128);          // EE*NCHUNK ints (8 KB)
  int* scanEx = (int*)(ws + 131072 + 128 + 8192);// EE*NCHUNK ints (8 KB)
  ushort* xbf = (ushort*)(ws + 262144);
  ushort* w1b = xbf + (size_t)TT * DD;
  ushort* w2b = w1b + (size_t)EE * FP * DD;
  ushort* w3b = w2b + (size_t)EE * FP * DD;
  ushort* hbf = w3b + (size_t)EE * DD * FP;

  gate_conv_kernel<<<TT / 4, 256, 0, stream>>>(x, Wg, bg, eidx, xbf);
  convw12_kernel<<<2048, 256, 0, stream>>>(W1, W2, w1b, w2b);
  convw3_kernel<<<2048, 256, 0, stream>>>(W3, w3b);
  hist_kernel<<<NCHUNK / 4, 256, 0, stream>>>(eidx, cnt);
  scan_kernel<<<1, 512, 0, stream>>>(cnt, scanEx, offs);
  scatter2_kernel<<<NCHUNK / 4, 256, 0, stream>>>(eidx, offs, scanEx, perm);
  ffn1_kernel<<<dim3(TT / 64, FP / 64, EE), 256, 0, stream>>>(xbf, w1b, w2b, perm, offs, hbf);
  ffn2_kernel<<<dim3(TT / 64, DD / 64, EE), 256, 0, stream>>>(hbf, w3b, perm, offs, out);
}